// Round 15
// baseline (270.798 us; speedup 1.0000x reference)
//
#include <hip/hip_runtime.h>
#include <hip/hip_bf16.h>

#define N_NODES  10000
#define N_EDGES  64000
#define N_GRAPHS 64
#define HID      64

typedef __attribute__((ext_vector_type(8))) short short8;
typedef __attribute__((ext_vector_type(4))) float f32x4;
typedef __attribute__((ext_vector_type(2))) float f32x2;

__device__ __forceinline__ float lrelu(float v){ return v > 0.f ? v : 0.01f*v; }

__device__ __forceinline__ unsigned short f2bf(float f){
    union { float f; unsigned u; } v; v.f = f;
    unsigned r = v.u + 0x7fff + ((v.u >> 16) & 1);
    return (unsigned short)(r >> 16);
}
__device__ __forceinline__ float bf2f(unsigned short s){
    union { unsigned u; float f; } v; v.u = ((unsigned)s) << 16;
    return v.f;
}
__device__ __forceinline__ short8 pack_bf8(float4 a, float4 b){
    short8 r;
    r[0]=(short)f2bf(a.x); r[1]=(short)f2bf(a.y); r[2]=(short)f2bf(a.z); r[3]=(short)f2bf(a.w);
    r[4]=(short)f2bf(b.x); r[5]=(short)f2bf(b.y); r[6]=(short)f2bf(b.z); r[7]=(short)f2bf(b.w);
    return r;
}

// ---------------- init: zero counts + counters | all small weight transposes ----------------
__global__ void __launch_bounds__(256) init_kernel(
        int* __restrict__ counts, int* __restrict__ pre_done, int* __restrict__ comb_done,
        const float* __restrict__ nfc_w, unsigned short* __restrict__ nfc_wt,
        const float* __restrict__ e1w1, unsigned short* __restrict__ w1t1,
        const float* __restrict__ e2w1, unsigned short* __restrict__ w1t2,
        const float* __restrict__ e1b2, unsigned short* __restrict__ b2t1,
        const float* __restrict__ e2b2, unsigned short* __restrict__ b2t2,
        const float* __restrict__ g1root, unsigned short* __restrict__ rootT1,
        const float* __restrict__ g2root, unsigned short* __restrict__ rootT2){
    int b = blockIdx.x, tid = threadIdx.x;
    if (b < 40){
        int i = b * 256 + tid;
        if (i < N_NODES) counts[i] = 0;
        if (b == 0 && tid == 0){ pre_done[0] = 0; comb_done[0] = 0; }
    } else if (b == 40){
        for (int idx = tid; idx < 8192; idx += 256){
            int o = idx >> 7, i = idx & 127;
            nfc_wt[idx] = f2bf(nfc_w[i * 64 + o]);
        }
    } else if (b <= 42){
        const float* w1 = (b == 42) ? e2w1 : e1w1;
        unsigned short* w1t = (b == 42) ? w1t2 : w1t1;
        for (int idx = tid; idx < 2048; idx += 256){
            int o = idx >> 5, k = idx & 31;
            w1t[idx] = f2bf(w1[k * 64 + o]);
        }
    } else if (b <= 44){
        const float* b2 = (b == 44) ? e2b2 : e1b2;
        unsigned short* b2t = (b == 44) ? b2t2 : b2t1;
        for (int idx = tid; idx < 4096; idx += 256){
            int o = idx >> 6, i = idx & 63;
            b2t[idx] = f2bf(b2[i * 64 + o]);
        }
    } else {
        const float* rt = (b == 46) ? g2root : g1root;
        unsigned short* rT = (b == 46) ? rootT2 : rootT1;
        for (int idx = tid; idx < 4096; idx += 256){
            int o = idx >> 6, i = idx & 63;
            rT[idx] = f2bf(rt[i * 64 + o]);
        }
    }
}

// ---------------- pre: nodeFC | t-GEMMs | w2conv | count; LAST BLOCK runs CSR scan ----------
#define PRE_NFC 157
#define PRE_TG  1000
#define PRE_W2C 128
#define PRE_CNT 250
#define PRE_NB  (PRE_NFC + PRE_TG + PRE_W2C + PRE_CNT)
__global__ void __launch_bounds__(256) pre_kernel(
        const float* __restrict__ x, const unsigned short* __restrict__ nfc_wt,
        const float* __restrict__ nfc_b, float* __restrict__ hx1,
        const float* __restrict__ ea,
        const unsigned short* __restrict__ w1t1, const float* __restrict__ e1b1, unsigned short* __restrict__ tp1,
        const unsigned short* __restrict__ w1t2, const float* __restrict__ e2b1, unsigned short* __restrict__ tp2,
        const float* __restrict__ e1w2, unsigned short* __restrict__ w2t1,
        const float* __restrict__ e2w2, unsigned short* __restrict__ w2t2,
        const int* __restrict__ src, int* __restrict__ counts,
        int* __restrict__ rowptr, int* __restrict__ cursor, int* __restrict__ pre_done){
    __shared__ float tile[64][65];
    __shared__ int part[256];
    __shared__ int lastf;
    int b = blockIdx.x, tid = threadIdx.x;
    int wid = tid >> 6, l = tid & 63;
    int m16 = l & 15, grp = l >> 4;
    if (b < PRE_NFC){
        int node = b * 64 + wid * 16 + m16;
        bool ok = node < N_NODES;
        short8 xb[4];
        #pragma unroll
        for (int kq = 0; kq < 4; ++kq){
            if (ok){
                const float* xp = x + (size_t)node * 128 + kq * 32 + grp * 8;
                xb[kq] = pack_bf8(*(const float4*)xp, *(const float4*)(xp + 4));
            } else {
                short8 z = {0,0,0,0,0,0,0,0}; xb[kq] = z;
            }
        }
        #pragma unroll
        for (int TB = 0; TB < 64; TB += 16){
            f32x4 acc = *(const f32x4*)(nfc_b + TB + grp * 4);
            #pragma unroll
            for (int kq = 0; kq < 4; ++kq){
                short8 af = *(const short8*)(nfc_wt + (TB + m16) * 128 + kq * 32 + grp * 8);
                acc = __builtin_amdgcn_mfma_f32_16x16x32_bf16(af, xb[kq], acc, 0, 0, 0);
            }
            f32x4 r;
            r[0] = lrelu(acc[0]); r[1] = lrelu(acc[1]); r[2] = lrelu(acc[2]); r[3] = lrelu(acc[3]);
            if (ok) *(f32x4*)(hx1 + ((size_t)node << 6) + TB + grp * 4) = r;
        }
    } else if (b < PRE_NFC + PRE_TG){
        int j = (b - PRE_NFC) * 64 + wid * 16 + m16;
        const float* row = ea + (size_t)j * 32 + grp * 8;
        short8 ef = pack_bf8(*(const float4*)row, *(const float4*)(row + 4));
        #pragma unroll
        for (int TB = 0; TB < 64; TB += 16){
            short8 wf1 = *(const short8*)(w1t1 + (TB + m16) * 32 + grp * 8);
            f32x4 a1 = *(const f32x4*)(e1b1 + TB + grp * 4);
            a1 = __builtin_amdgcn_mfma_f32_16x16x32_bf16(wf1, ef, a1, 0, 0, 0);
            uint2 p;
            p.x = (unsigned)f2bf(fmaxf(a1[0], 0.f)) | ((unsigned)f2bf(fmaxf(a1[1], 0.f)) << 16);
            p.y = (unsigned)f2bf(fmaxf(a1[2], 0.f)) | ((unsigned)f2bf(fmaxf(a1[3], 0.f)) << 16);
            *(uint2*)(tp1 + ((size_t)j << 6) + TB + grp * 4) = p;
            short8 wf2 = *(const short8*)(w1t2 + (TB + m16) * 32 + grp * 8);
            f32x4 a2 = *(const f32x4*)(e2b1 + TB + grp * 4);
            a2 = __builtin_amdgcn_mfma_f32_16x16x32_bf16(wf2, ef, a2, 0, 0, 0);
            p.x = (unsigned)f2bf(fmaxf(a2[0], 0.f)) | ((unsigned)f2bf(fmaxf(a2[1], 0.f)) << 16);
            p.y = (unsigned)f2bf(fmaxf(a2[2], 0.f)) | ((unsigned)f2bf(fmaxf(a2[3], 0.f)) << 16);
            *(uint2*)(tp2 + ((size_t)j << 6) + TB + grp * 4) = p;
        }
    } else if (b < PRE_NFC + PRE_TG + PRE_W2C){
        int bb = b - PRE_NFC - PRE_TG;
        int k = bb & 63;
        const float* srcw = ((bb < 64) ? e1w2 : e2w2) + (size_t)k * 4096;
        unsigned short* dstw = (bb < 64) ? w2t1 : w2t2;
        for (int idx = tid; idx < 4096; idx += 256) tile[idx >> 6][idx & 63] = srcw[idx];
        __syncthreads();
        for (int idx = tid; idx < 4096; idx += 256){
            int o = idx >> 6, i = idx & 63;
            dstw[((size_t)(k * 64 + o) << 6) + i] = f2bf(tile[i][o]);
        }
    } else {
        int e = (b - PRE_NFC - PRE_TG - PRE_W2C) * 256 + tid;
        if (e < N_EDGES) atomicAdd(&counts[src[e]], 1);
    }

    // -------- last-block CSR scan (rowptr from counts; zero cursor) --------
    __syncthreads();                            // drain this block's mem ops (vmcnt before barrier)
    if (tid == 0){
        __threadfence();
        lastf = (atomicAdd(pre_done, 1) == PRE_NB - 1) ? 1 : 0;
    }
    __syncthreads();
    if (lastf){
        const int CH = 40;                      // 256*40 >= 10000
        int base = tid * CH;
        int cnt[CH];
        int s = 0;
        #pragma unroll
        for (int i = 0; i < CH; ++i){
            int idx = base + i;
            int c = (idx < N_NODES) ? atomicAdd(&counts[idx], 0) : 0;  // coherent read
            cnt[i] = c; s += c;
        }
        part[tid] = s; __syncthreads();
        for (int off = 1; off < 256; off <<= 1){
            int v = (tid >= off) ? part[tid - off] : 0;
            __syncthreads();
            part[tid] += v;
            __syncthreads();
        }
        int run = part[tid] - s;
        #pragma unroll
        for (int i = 0; i < CH; ++i){
            int idx = base + i;
            if (idx < N_NODES){ rowptr[idx] = run; cursor[idx] = 0; run += cnt[i]; }
        }
        if (tid == 255) rowptr[N_NODES] = run;
    }
}

// ---------------- per-layer: hb2(MFMA)+agg0 | gmat (MFMA -> fp8 G) | scatter / hg0 ---------
#define NBH2 157
#define NBG  (157 * 8)
template<int L2FLAG, int SCAT>
__global__ void __launch_bounds__(256) layerA_kernel(
        const float* __restrict__ hx, const unsigned short* __restrict__ b2t,
        float* __restrict__ hb2, float* __restrict__ agg,
        const unsigned short* __restrict__ w2t, unsigned char* __restrict__ G,
        float* __restrict__ hg,
        const int* __restrict__ src, const int* __restrict__ dst,
        const int* __restrict__ rowptr, int* __restrict__ cursor,
        int* __restrict__ eidx, int* __restrict__ dsts){
    __shared__ unsigned stgu[8192];            // 32 KB (gmat branch only)
    int b = blockIdx.x, tid = threadIdx.x;
    int wid = tid >> 6, l = tid & 63;
    int m16 = l & 15, grp = l >> 4;

    if (b < NBH2){
        int node = b * 64 + wid * 16 + m16;
        short8 h0 = {0,0,0,0,0,0,0,0}, h1 = {0,0,0,0,0,0,0,0};
        if (node < N_NODES){
            const float* hp = hx + ((size_t)node << 6) + grp * 8;
            h0 = pack_bf8(*(const float4*)hp, *(const float4*)(hp + 4));
            h1 = pack_bf8(*(const float4*)(hp + 32), *(const float4*)(hp + 36));
        }
        #pragma unroll
        for (int TB = 0; TB < 64; TB += 16){
            short8 c0 = *(const short8*)(b2t + (TB + m16) * 64 + grp * 8);
            short8 c1 = *(const short8*)(b2t + (TB + m16) * 64 + 32 + grp * 8);
            f32x4 acc = {0.f, 0.f, 0.f, 0.f};
            acc = __builtin_amdgcn_mfma_f32_16x16x32_bf16(c0, h0, acc, 0, 0, 0);
            acc = __builtin_amdgcn_mfma_f32_16x16x32_bf16(c1, h1, acc, 0, 0, 0);
            if (node < N_NODES) *(f32x4*)(hb2 + ((size_t)node << 6) + TB + grp * 4) = acc;
        }
        f32x4 z = {0.f, 0.f, 0.f, 0.f};
        #pragma unroll
        for (int q = 0; q < 4; ++q){
            int chunk = q * 256 + tid;
            int n = b * 64 + (chunk >> 4), c = (chunk & 15) * 4;
            if (n < N_NODES) *(f32x4*)(agg + ((size_t)n << 6) + c) = z;
        }
    } else if (b < NBH2 + NBG){
        int g = b - NBH2;
        int bx = g >> 3, by = g & 7;
        int n0 = bx * 64;
        int cb = by * 512;

        short8 bf0[4], bf1[4];
        #pragma unroll
        for (int ng = 0; ng < 4; ++ng){
            int node = n0 + ng * 16 + m16;
            short8 b0 = {0,0,0,0,0,0,0,0}, b1v = {0,0,0,0,0,0,0,0};
            if (node < N_NODES){
                const float* hp = hx + ((size_t)node << 6) + grp * 8;
                b0  = pack_bf8(*(const float4*)hp, *(const float4*)(hp + 4));
                b1v = pack_bf8(*(const float4*)(hp + 32), *(const float4*)(hp + 36));
            }
            bf0[ng] = b0; bf1[ng] = b1v;
        }

        #pragma unroll
        for (int t = 0; t < 8; ++t){
            int TB = cb + t * 64 + wid * 16;
            const unsigned short* ap = w2t + ((size_t)(TB + m16) << 6) + grp * 8;
            short8 a0 = *(const short8*)ap;
            short8 a1 = *(const short8*)(ap + 32);
            int colLocal = t * 64 + wid * 16 + grp * 4;
            #pragma unroll
            for (int ng = 0; ng < 4; ++ng){
                f32x4 acc = {0.f, 0.f, 0.f, 0.f};
                acc = __builtin_amdgcn_mfma_f32_16x16x32_bf16(a0, bf0[ng], acc, 0, 0, 0);
                acc = __builtin_amdgcn_mfma_f32_16x16x32_bf16(a1, bf1[ng], acc, 0, 0, 0);
                int pk = __builtin_amdgcn_cvt_pk_fp8_f32(acc[0], acc[1], 0, false);
                pk = __builtin_amdgcn_cvt_pk_fp8_f32(acc[2], acc[3], pk, true);
                int row = ng * 16 + m16;
                int dw = ((row << 7) + (colLocal >> 2)) ^ ((row & 7) << 2);
                stgu[dw] = (unsigned)pk;
            }
        }
        __syncthreads();
        #pragma unroll
        for (int s2 = 0; s2 < 8; ++s2){
            int ci = s2 * 256 + tid;
            int row = ci >> 5;
            int c = ci & 31;
            int node = n0 + row;
            int dwb = ((row << 7) + (c << 2)) ^ ((row & 7) << 2);
            uint4 v = *(const uint4*)&stgu[dwb];
            if (node < N_NODES)
                *(uint4*)(G + (size_t)node * 4096 + cb + c * 16) = v;
        }
    } else if (SCAT){
        int e = (b - NBH2 - NBG) * 256 + tid;
        if (e < N_EDGES){
            int s = src[e];
            int j = rowptr[s] + atomicAdd(&cursor[s], 1);
            eidx[j] = e; dsts[j] = dst[e];
        }
    } else if (L2FLAG){
        for (int i = tid; i < N_GRAPHS * 64; i += 256) hg[i] = 0.f;
    }
}

// ---------------- msg: G row via 4 coalesced uint4 loads + LDS byte-transpose -------------
__global__ void __launch_bounds__(64) msg_csr_kernel(
        const unsigned short* __restrict__ tp, const unsigned char* __restrict__ G,
        const float* __restrict__ hb2, const int* __restrict__ rowptr,
        const int* __restrict__ eidx, const int* __restrict__ dsts,
        float* __restrict__ agg){
    int s = blockIdx.x;
    int o = threadIdx.x;
    __shared__ unsigned char gl[4096] __attribute__((aligned(16)));
    __shared__ unsigned short ts[64] __attribute__((aligned(16)));
    int r0 = rowptr[s], r1 = rowptr[s + 1];
    if (r0 == r1) return;
    const uint4* gs = (const uint4*)(G + (size_t)s * 4096);
    uint4* gld = (uint4*)gl;
    #pragma unroll
    for (int i = 0; i < 4; ++i) gld[i * 64 + o] = gs[i * 64 + o];   // 4 KB coalesced
    // single-wave block: LDS write->read in-order within wave
    float g[64];
    #pragma unroll
    for (int k = 0; k < 64; k += 2){
        unsigned b0 = gl[(k << 6) + o];
        unsigned b1 = gl[((k + 1) << 6) + o];
        f32x2 d = __builtin_amdgcn_cvt_pk_f32_fp8((int)(b0 | (b1 << 8)), false);
        g[k] = d[0]; g[k + 1] = d[1];
    }
    float hb = hb2[((size_t)s << 6) + o];
    for (int j = r0; j < r1; ++j){
        int e = eidx[j];
        ts[o] = tp[((size_t)e << 6) + o];
        float acc = hb;
        #pragma unroll
        for (int k8 = 0; k8 < 8; ++k8){
            short8 tv = *(const short8*)&ts[k8 * 8];
            #pragma unroll
            for (int u = 0; u < 8; ++u) acc += bf2f((unsigned short)tv[u]) * g[k8 * 8 + u];
        }
        atomicAdd(&agg[((size_t)dsts[j] << 6) + o], acc);
    }
}

// ---------------- combine (MFMA root GEMM); L2: LDS-staged pooling + last-block head ------
template<int L2>
__global__ void __launch_bounds__(256) combine_kernel(
        const float* __restrict__ agg, const float* __restrict__ hx,
        const unsigned short* __restrict__ rootT, const float* __restrict__ bias,
        float* __restrict__ outp, const int* __restrict__ batch, float* __restrict__ hg,
        const float* __restrict__ fc1w, const float* __restrict__ fc1b,
        const float* __restrict__ fc2w, const float* __restrict__ fc2b,
        float* __restrict__ out, int* __restrict__ comb_done){
    __shared__ float otile[64][65];
    __shared__ int lastf;
    int b = blockIdx.x, tid = threadIdx.x;
    int wid = tid >> 6, l = tid & 63;
    int m16 = l & 15, grp = l >> 4;
    int node = b * 64 + wid * 16 + m16;
    int lnode = wid * 16 + m16;
    bool ok = node < N_NODES;
    short8 h0 = {0,0,0,0,0,0,0,0}, h1 = {0,0,0,0,0,0,0,0};
    if (ok){
        const float* hp = hx + ((size_t)node << 6) + grp * 8;
        h0 = pack_bf8(*(const float4*)hp, *(const float4*)(hp + 4));
        h1 = pack_bf8(*(const float4*)(hp + 32), *(const float4*)(hp + 36));
    }
    #pragma unroll
    for (int TB = 0; TB < 64; TB += 16){
        short8 c0 = *(const short8*)(rootT + (TB + m16) * 64 + grp * 8);
        short8 c1 = *(const short8*)(rootT + (TB + m16) * 64 + 32 + grp * 8);
        f32x4 acc;
        if (ok){
            f32x4 av = *(const f32x4*)(agg + ((size_t)node << 6) + TB + grp * 4);
            f32x4 bv = *(const f32x4*)(bias + TB + grp * 4);
            acc[0] = av[0] + bv[0]; acc[1] = av[1] + bv[1];
            acc[2] = av[2] + bv[2]; acc[3] = av[3] + bv[3];
        } else {
            acc[0] = acc[1] = acc[2] = acc[3] = 0.f;
        }
        acc = __builtin_amdgcn_mfma_f32_16x16x32_bf16(c0, h0, acc, 0, 0, 0);
        acc = __builtin_amdgcn_mfma_f32_16x16x32_bf16(c1, h1, acc, 0, 0, 0);
        if (L2){
            #pragma unroll
            for (int r = 0; r < 4; ++r) otile[lnode][TB + grp * 4 + r] = lrelu(acc[r]);
        } else if (ok){
            f32x4 rv;
            rv[0] = lrelu(acc[0]); rv[1] = lrelu(acc[1]);
            rv[2] = lrelu(acc[2]); rv[3] = lrelu(acc[3]);
            *(f32x4*)(outp + ((size_t)node << 6) + TB + grp * 4) = rv;
        }
    }
    if (L2){
        __syncthreads();
        #pragma unroll
        for (int p = 0; p < 16; ++p){
            int ln = wid * 16 + p;
            int n = b * 64 + ln;
            if (n < N_NODES)
                atomicAdd(&hg[batch[n] * 64 + l], otile[ln][l]);
        }
        // -------- last block computes the head --------
        __syncthreads();                        // drain this block's atomics
        if (tid == 0){
            __threadfence();
            lastf = (atomicAdd(comb_done, 1) == 156) ? 1 : 0;
        }
        __syncthreads();
        if (lastf && tid < 64){
            int gidx = tid;
            float row[64];
            #pragma unroll
            for (int i = 0; i < 64; ++i) row[i] = atomicAdd(&hg[gidx * 64 + i], 0.f); // coherent read
            float h1v[32];
            #pragma unroll
            for (int j = 0; j < 32; ++j){
                float a = fc1b[j];
                #pragma unroll 8
                for (int i = 0; i < 64; ++i) a += row[i] * fc1w[i * 32 + j];
                h1v[j] = lrelu(a);
            }
            float ov = fc2b[0];
            #pragma unroll
            for (int j = 0; j < 32; ++j) ov += h1v[j] * fc2w[j];
            out[gidx] = ov;
        }
    }
}

extern "C" void kernel_launch(void* const* d_in, const int* in_sizes, int n_in,
                              void* d_out, int out_size, void* d_ws, size_t ws_size,
                              hipStream_t stream){
    const float* x      = (const float*)d_in[0];
    const int*   ei     = (const int*)  d_in[1];
    const float* ea     = (const float*)d_in[2];
    const int*   batch  = (const int*)  d_in[3];
    const float* nfc_w  = (const float*)d_in[4];
    const float* nfc_b  = (const float*)d_in[5];
    const float* e1w1   = (const float*)d_in[6];
    const float* e1b1   = (const float*)d_in[7];
    const float* e1w2   = (const float*)d_in[8];
    const float* e1b2   = (const float*)d_in[9];
    const float* g1root = (const float*)d_in[10];
    const float* g1bias = (const float*)d_in[11];
    const float* e2w1   = (const float*)d_in[12];
    const float* e2b1   = (const float*)d_in[13];
    const float* e2w2   = (const float*)d_in[14];
    const float* e2b2   = (const float*)d_in[15];
    const float* g2root = (const float*)d_in[16];
    const float* g2bias = (const float*)d_in[17];
    const float* fc1w   = (const float*)d_in[18];
    const float* fc1b   = (const float*)d_in[19];
    const float* fc2w   = (const float*)d_in[20];
    const float* fc2b   = (const float*)d_in[21];
    float* out = (float*)d_out;

    const int* src = ei;
    const int* dst = ei + N_EDGES;

    // workspace carve-up
    char* ws = (char*)d_ws;
    float* hx1 = (float*)ws;               ws += (size_t)N_NODES * 64 * 4;
    float* hx2 = (float*)ws;               ws += (size_t)N_NODES * 64 * 4;
    unsigned short* tp1 = (unsigned short*)ws; ws += (size_t)N_EDGES * 64 * 2;
    unsigned short* tp2 = (unsigned short*)ws; ws += (size_t)N_EDGES * 64 * 2;
    float* hb2 = (float*)ws;               ws += (size_t)N_NODES * 64 * 4;
    float* agg = (float*)ws;               ws += (size_t)N_NODES * 64 * 4;
    float* hg  = (float*)ws;               ws += (size_t)N_GRAPHS * 64 * 4;
    unsigned short* w2t1 = (unsigned short*)ws; ws += (size_t)64 * 64 * 64 * 2;
    unsigned short* w2t2 = (unsigned short*)ws; ws += (size_t)64 * 64 * 64 * 2;
    unsigned short* nfc_wt = (unsigned short*)ws; ws += (size_t)8192 * 2;
    unsigned short* w1t1 = (unsigned short*)ws; ws += (size_t)2048 * 2;
    unsigned short* w1t2 = (unsigned short*)ws; ws += (size_t)2048 * 2;
    unsigned short* b2t1 = (unsigned short*)ws; ws += (size_t)4096 * 2;
    unsigned short* b2t2 = (unsigned short*)ws; ws += (size_t)4096 * 2;
    unsigned short* rootT1 = (unsigned short*)ws; ws += (size_t)4096 * 2;
    unsigned short* rootT2 = (unsigned short*)ws; ws += (size_t)4096 * 2;
    int* counts = (int*)ws;                ws += (size_t)10240 * 4;
    int* cursor = (int*)ws;                ws += (size_t)10240 * 4;
    int* rowptr = (int*)ws;                ws += (size_t)10240 * 4;
    int* eidx   = (int*)ws;                ws += (size_t)N_EDGES * 4;
    int* dsts   = (int*)ws;                ws += (size_t)N_EDGES * 4;
    int* pre_done  = (int*)ws;             ws += 256;
    int* comb_done = (int*)ws;             ws += 256;
    unsigned char* G = (unsigned char*)ws;  // 41 MB fp8

    // 1: init (zero counts/counters + weight transposes)
    init_kernel<<<47, 256, 0, stream>>>(counts, pre_done, comb_done, nfc_w, nfc_wt,
        e1w1, w1t1, e2w1, w1t2, e1b2, b2t1, e2b2, b2t2, g1root, rootT1, g2root, rootT2);
    // 2: pre (nodeFC | t-GEMMs | w2conv | count) + last-block scan
    pre_kernel<<<PRE_NB, 256, 0, stream>>>(
        x, nfc_wt, nfc_b, hx1, ea, w1t1, e1b1, tp1, w1t2, e2b1, tp2,
        e1w2, w2t1, e2w2, w2t2, src, counts, rowptr, cursor, pre_done);

    // ---------- layer 1 (3,4,5) ----------
    layerA_kernel<0, 1><<<NBH2 + NBG + 250, 256, 0, stream>>>(
        hx1, b2t1, hb2, agg, w2t1, G, nullptr, src, dst, rowptr, cursor, eidx, dsts);
    msg_csr_kernel<<<N_NODES, 64, 0, stream>>>(tp1, G, hb2, rowptr, eidx, dsts, agg);
    combine_kernel<0><<<157, 256, 0, stream>>>(agg, hx1, rootT1, g1bias, hx2, batch, nullptr,
                                               nullptr, nullptr, nullptr, nullptr, nullptr, nullptr);

    // ---------- layer 2 (6,7,8) ----------
    layerA_kernel<1, 0><<<NBH2 + NBG + 1, 256, 0, stream>>>(
        hx2, b2t2, hb2, agg, w2t2, G, hg, src, dst, rowptr, cursor, eidx, dsts);
    msg_csr_kernel<<<N_NODES, 64, 0, stream>>>(tp2, G, hb2, rowptr, eidx, dsts, agg);
    combine_kernel<1><<<157, 256, 0, stream>>>(agg, hx2, rootT2, g2bias, nullptr, batch, hg,
                                               fc1w, fc1b, fc2w, fc2b, out, comb_done);
}

// Round 16
// 214.992 us; speedup vs baseline: 1.2596x; 1.2596x over previous
//
#include <hip/hip_runtime.h>
#include <hip/hip_bf16.h>

#define N_NODES  10000
#define N_EDGES  64000
#define N_GRAPHS 64
#define HID      64

typedef __attribute__((ext_vector_type(8))) short short8;
typedef __attribute__((ext_vector_type(4))) float f32x4;
typedef __attribute__((ext_vector_type(2))) float f32x2;

__device__ __forceinline__ float lrelu(float v){ return v > 0.f ? v : 0.01f*v; }

__device__ __forceinline__ unsigned short f2bf(float f){
    union { float f; unsigned u; } v; v.f = f;
    unsigned r = v.u + 0x7fff + ((v.u >> 16) & 1);
    return (unsigned short)(r >> 16);
}
__device__ __forceinline__ float bf2f(unsigned short s){
    union { unsigned u; float f; } v; v.u = ((unsigned)s) << 16;
    return v.f;
}
__device__ __forceinline__ short8 pack_bf8(float4 a, float4 b){
    short8 r;
    r[0]=(short)f2bf(a.x); r[1]=(short)f2bf(a.y); r[2]=(short)f2bf(a.z); r[3]=(short)f2bf(a.w);
    r[4]=(short)f2bf(b.x); r[5]=(short)f2bf(b.y); r[6]=(short)f2bf(b.z); r[7]=(short)f2bf(b.w);
    return r;
}

// ---------------- init: zero counts | all small weight transposes (bf16) ----------------
__global__ void __launch_bounds__(256) init_kernel(
        int* __restrict__ counts,
        const float* __restrict__ nfc_w, unsigned short* __restrict__ nfc_wt,
        const float* __restrict__ e1w1, unsigned short* __restrict__ w1t1,
        const float* __restrict__ e2w1, unsigned short* __restrict__ w1t2,
        const float* __restrict__ e1b2, unsigned short* __restrict__ b2t1,
        const float* __restrict__ e2b2, unsigned short* __restrict__ b2t2,
        const float* __restrict__ g1root, unsigned short* __restrict__ rootT1,
        const float* __restrict__ g2root, unsigned short* __restrict__ rootT2){
    int b = blockIdx.x, tid = threadIdx.x;
    if (b < 40){
        int i = b * 256 + tid;
        if (i < N_NODES) counts[i] = 0;
    } else if (b == 40){
        for (int idx = tid; idx < 8192; idx += 256){
            int o = idx >> 7, i = idx & 127;
            nfc_wt[idx] = f2bf(nfc_w[i * 64 + o]);
        }
    } else if (b <= 42){
        const float* w1 = (b == 42) ? e2w1 : e1w1;
        unsigned short* w1t = (b == 42) ? w1t2 : w1t1;
        for (int idx = tid; idx < 2048; idx += 256){
            int o = idx >> 5, k = idx & 31;
            w1t[idx] = f2bf(w1[k * 64 + o]);
        }
    } else if (b <= 44){
        const float* b2 = (b == 44) ? e2b2 : e1b2;
        unsigned short* b2t = (b == 44) ? b2t2 : b2t1;
        for (int idx = tid; idx < 4096; idx += 256){
            int o = idx >> 6, i = idx & 63;
            b2t[idx] = f2bf(b2[i * 64 + o]);
        }
    } else {
        const float* rt = (b == 46) ? g2root : g1root;
        unsigned short* rT = (b == 46) ? rootT2 : rootT1;
        for (int idx = tid; idx < 4096; idx += 256){
            int o = idx >> 6, i = idx & 63;
            rT[idx] = f2bf(rt[i * 64 + o]);
        }
    }
}

// ---------------- pre: nodeFC (MFMA) | both t-GEMMs (MFMA, orig order) | w2conv | count ----
#define PRE_NFC 157
#define PRE_TG  1000
#define PRE_W2C 128
#define PRE_CNT 250
__global__ void __launch_bounds__(256) pre_kernel(
        const float* __restrict__ x, const unsigned short* __restrict__ nfc_wt,
        const float* __restrict__ nfc_b, float* __restrict__ hx1,
        const float* __restrict__ ea,
        const unsigned short* __restrict__ w1t1, const float* __restrict__ e1b1, unsigned short* __restrict__ tp1,
        const unsigned short* __restrict__ w1t2, const float* __restrict__ e2b1, unsigned short* __restrict__ tp2,
        const float* __restrict__ e1w2, unsigned short* __restrict__ w2t1,
        const float* __restrict__ e2w2, unsigned short* __restrict__ w2t2,
        const int* __restrict__ src, int* __restrict__ counts){
    __shared__ float tile[64][65];
    int b = blockIdx.x, tid = threadIdx.x;
    int wid = tid >> 6, l = tid & 63;
    int m16 = l & 15, grp = l >> 4;
    if (b < PRE_NFC){
        int node = b * 64 + wid * 16 + m16;
        bool ok = node < N_NODES;
        short8 xb[4];
        #pragma unroll
        for (int kq = 0; kq < 4; ++kq){
            if (ok){
                const float* xp = x + (size_t)node * 128 + kq * 32 + grp * 8;
                xb[kq] = pack_bf8(*(const float4*)xp, *(const float4*)(xp + 4));
            } else {
                short8 z = {0,0,0,0,0,0,0,0}; xb[kq] = z;
            }
        }
        #pragma unroll
        for (int TB = 0; TB < 64; TB += 16){
            f32x4 acc = *(const f32x4*)(nfc_b + TB + grp * 4);
            #pragma unroll
            for (int kq = 0; kq < 4; ++kq){
                short8 af = *(const short8*)(nfc_wt + (TB + m16) * 128 + kq * 32 + grp * 8);
                acc = __builtin_amdgcn_mfma_f32_16x16x32_bf16(af, xb[kq], acc, 0, 0, 0);
            }
            f32x4 r;
            r[0] = lrelu(acc[0]); r[1] = lrelu(acc[1]); r[2] = lrelu(acc[2]); r[3] = lrelu(acc[3]);
            if (ok) *(f32x4*)(hx1 + ((size_t)node << 6) + TB + grp * 4) = r;
        }
    } else if (b < PRE_NFC + PRE_TG){
        int j = (b - PRE_NFC) * 64 + wid * 16 + m16;
        const float* row = ea + (size_t)j * 32 + grp * 8;
        short8 ef = pack_bf8(*(const float4*)row, *(const float4*)(row + 4));
        #pragma unroll
        for (int TB = 0; TB < 64; TB += 16){
            short8 wf1 = *(const short8*)(w1t1 + (TB + m16) * 32 + grp * 8);
            f32x4 a1 = *(const f32x4*)(e1b1 + TB + grp * 4);
            a1 = __builtin_amdgcn_mfma_f32_16x16x32_bf16(wf1, ef, a1, 0, 0, 0);
            uint2 p;
            p.x = (unsigned)f2bf(fmaxf(a1[0], 0.f)) | ((unsigned)f2bf(fmaxf(a1[1], 0.f)) << 16);
            p.y = (unsigned)f2bf(fmaxf(a1[2], 0.f)) | ((unsigned)f2bf(fmaxf(a1[3], 0.f)) << 16);
            *(uint2*)(tp1 + ((size_t)j << 6) + TB + grp * 4) = p;
            short8 wf2 = *(const short8*)(w1t2 + (TB + m16) * 32 + grp * 8);
            f32x4 a2 = *(const f32x4*)(e2b1 + TB + grp * 4);
            a2 = __builtin_amdgcn_mfma_f32_16x16x32_bf16(wf2, ef, a2, 0, 0, 0);
            p.x = (unsigned)f2bf(fmaxf(a2[0], 0.f)) | ((unsigned)f2bf(fmaxf(a2[1], 0.f)) << 16);
            p.y = (unsigned)f2bf(fmaxf(a2[2], 0.f)) | ((unsigned)f2bf(fmaxf(a2[3], 0.f)) << 16);
            *(uint2*)(tp2 + ((size_t)j << 6) + TB + grp * 4) = p;
        }
    } else if (b < PRE_NFC + PRE_TG + PRE_W2C){
        int bb = b - PRE_NFC - PRE_TG;
        int k = bb & 63;
        const float* srcw = ((bb < 64) ? e1w2 : e2w2) + (size_t)k * 4096;
        unsigned short* dstw = (bb < 64) ? w2t1 : w2t2;
        for (int idx = tid; idx < 4096; idx += 256) tile[idx >> 6][idx & 63] = srcw[idx];
        __syncthreads();
        for (int idx = tid; idx < 4096; idx += 256){
            int o = idx >> 6, i = idx & 63;
            dstw[((size_t)(k * 64 + o) << 6) + i] = f2bf(tile[i][o]);
        }
    } else {
        int e = (b - PRE_NFC - PRE_TG - PRE_W2C) * 256 + tid;
        if (e < N_EDGES) atomicAdd(&counts[src[e]], 1);
    }
}

// scan rowptr from counts (plain loads — kernel boundary gives coherence); zero cursor
__global__ void csr_scan_kernel(const int* __restrict__ counts, int* __restrict__ rowptr,
                                int* __restrict__ cursor){
    __shared__ int part[256];
    int tid = threadIdx.x;
    const int CH = (N_NODES + 255) / 256;      // 40
    int base = tid * CH, s = 0;
    for (int i = 0; i < CH; ++i){ int idx = base + i; if (idx < N_NODES){ cursor[idx] = 0; s += counts[idx]; } }
    part[tid] = s; __syncthreads();
    for (int off = 1; off < 256; off <<= 1){
        int v = (tid >= off) ? part[tid - off] : 0;
        __syncthreads();
        part[tid] += v;
        __syncthreads();
    }
    int run = part[tid] - s;
    for (int i = 0; i < CH; ++i){ int idx = base + i; if (idx < N_NODES){ rowptr[idx] = run; run += counts[idx]; } }
    if (tid == 255) rowptr[N_NODES] = run;
}

// ---------------- per-layer: hb2(MFMA)+agg0 | gmat (MFMA -> fp8 G) | scatter / hg0 ---------
#define NBH2 157
#define NBG  (157 * 8)
template<int L2FLAG, int SCAT>
__global__ void __launch_bounds__(256) layerA_kernel(
        const float* __restrict__ hx, const unsigned short* __restrict__ b2t,
        float* __restrict__ hb2, float* __restrict__ agg,
        const unsigned short* __restrict__ w2t, unsigned char* __restrict__ G,
        float* __restrict__ hg,
        const int* __restrict__ src, const int* __restrict__ dst,
        const int* __restrict__ rowptr, int* __restrict__ cursor,
        int* __restrict__ eidx, int* __restrict__ dsts){
    __shared__ unsigned stgu[8192];            // 32 KB (gmat branch only)
    int b = blockIdx.x, tid = threadIdx.x;
    int wid = tid >> 6, l = tid & 63;
    int m16 = l & 15, grp = l >> 4;

    if (b < NBH2){
        int node = b * 64 + wid * 16 + m16;
        short8 h0 = {0,0,0,0,0,0,0,0}, h1 = {0,0,0,0,0,0,0,0};
        if (node < N_NODES){
            const float* hp = hx + ((size_t)node << 6) + grp * 8;
            h0 = pack_bf8(*(const float4*)hp, *(const float4*)(hp + 4));
            h1 = pack_bf8(*(const float4*)(hp + 32), *(const float4*)(hp + 36));
        }
        #pragma unroll
        for (int TB = 0; TB < 64; TB += 16){
            short8 c0 = *(const short8*)(b2t + (TB + m16) * 64 + grp * 8);
            short8 c1 = *(const short8*)(b2t + (TB + m16) * 64 + 32 + grp * 8);
            f32x4 acc = {0.f, 0.f, 0.f, 0.f};
            acc = __builtin_amdgcn_mfma_f32_16x16x32_bf16(c0, h0, acc, 0, 0, 0);
            acc = __builtin_amdgcn_mfma_f32_16x16x32_bf16(c1, h1, acc, 0, 0, 0);
            if (node < N_NODES) *(f32x4*)(hb2 + ((size_t)node << 6) + TB + grp * 4) = acc;
        }
        f32x4 z = {0.f, 0.f, 0.f, 0.f};
        #pragma unroll
        for (int q = 0; q < 4; ++q){
            int chunk = q * 256 + tid;
            int n = b * 64 + (chunk >> 4), c = (chunk & 15) * 4;
            if (n < N_NODES) *(f32x4*)(agg + ((size_t)n << 6) + c) = z;
        }
    } else if (b < NBH2 + NBG){
        int g = b - NBH2;
        int bx = g >> 3, by = g & 7;
        int n0 = bx * 64;
        int cb = by * 512;

        short8 bf0[4], bf1[4];
        #pragma unroll
        for (int ng = 0; ng < 4; ++ng){
            int node = n0 + ng * 16 + m16;
            short8 b0 = {0,0,0,0,0,0,0,0}, b1v = {0,0,0,0,0,0,0,0};
            if (node < N_NODES){
                const float* hp = hx + ((size_t)node << 6) + grp * 8;
                b0  = pack_bf8(*(const float4*)hp, *(const float4*)(hp + 4));
                b1v = pack_bf8(*(const float4*)(hp + 32), *(const float4*)(hp + 36));
            }
            bf0[ng] = b0; bf1[ng] = b1v;
        }

        #pragma unroll
        for (int t = 0; t < 8; ++t){
            int TB = cb + t * 64 + wid * 16;
            const unsigned short* ap = w2t + ((size_t)(TB + m16) << 6) + grp * 8;
            short8 a0 = *(const short8*)ap;
            short8 a1 = *(const short8*)(ap + 32);
            int colLocal = t * 64 + wid * 16 + grp * 4;
            #pragma unroll
            for (int ng = 0; ng < 4; ++ng){
                f32x4 acc = {0.f, 0.f, 0.f, 0.f};
                acc = __builtin_amdgcn_mfma_f32_16x16x32_bf16(a0, bf0[ng], acc, 0, 0, 0);
                acc = __builtin_amdgcn_mfma_f32_16x16x32_bf16(a1, bf1[ng], acc, 0, 0, 0);
                int pk = __builtin_amdgcn_cvt_pk_fp8_f32(acc[0], acc[1], 0, false);
                pk = __builtin_amdgcn_cvt_pk_fp8_f32(acc[2], acc[3], pk, true);
                int row = ng * 16 + m16;
                int dw = ((row << 7) + (colLocal >> 2)) ^ ((row & 7) << 2);
                stgu[dw] = (unsigned)pk;
            }
        }
        __syncthreads();
        #pragma unroll
        for (int s2 = 0; s2 < 8; ++s2){
            int ci = s2 * 256 + tid;
            int row = ci >> 5;
            int c = ci & 31;
            int node = n0 + row;
            int dwb = ((row << 7) + (c << 2)) ^ ((row & 7) << 2);
            uint4 v = *(const uint4*)&stgu[dwb];
            if (node < N_NODES)
                *(uint4*)(G + (size_t)node * 4096 + cb + c * 16) = v;
        }
    } else if (SCAT){
        int e = (b - NBH2 - NBG) * 256 + tid;
        if (e < N_EDGES){
            int s = src[e];
            int j = rowptr[s] + atomicAdd(&cursor[s], 1);
            eidx[j] = e; dsts[j] = dst[e];
        }
    } else if (L2FLAG){
        for (int i = tid; i < N_GRAPHS * 64; i += 256) hg[i] = 0.f;
    }
}

// ---------------- msg: G row via 4 coalesced uint4 loads + LDS byte-transpose -------------
__global__ void __launch_bounds__(64) msg_csr_kernel(
        const unsigned short* __restrict__ tp, const unsigned char* __restrict__ G,
        const float* __restrict__ hb2, const int* __restrict__ rowptr,
        const int* __restrict__ eidx, const int* __restrict__ dsts,
        float* __restrict__ agg){
    int s = blockIdx.x;
    int o = threadIdx.x;
    __shared__ unsigned char gl[4096] __attribute__((aligned(16)));
    __shared__ unsigned short ts[64] __attribute__((aligned(16)));
    int r0 = rowptr[s], r1 = rowptr[s + 1];
    if (r0 == r1) return;
    const uint4* gs = (const uint4*)(G + (size_t)s * 4096);
    uint4* gld = (uint4*)gl;
    #pragma unroll
    for (int i = 0; i < 4; ++i) gld[i * 64 + o] = gs[i * 64 + o];   // 4 KB coalesced
    float g[64];
    #pragma unroll
    for (int k = 0; k < 64; k += 2){
        unsigned b0 = gl[(k << 6) + o];
        unsigned b1 = gl[((k + 1) << 6) + o];
        f32x2 d = __builtin_amdgcn_cvt_pk_f32_fp8((int)(b0 | (b1 << 8)), false);
        g[k] = d[0]; g[k + 1] = d[1];
    }
    float hb = hb2[((size_t)s << 6) + o];
    for (int j = r0; j < r1; ++j){
        int e = eidx[j];
        ts[o] = tp[((size_t)e << 6) + o];
        float acc = hb;
        #pragma unroll
        for (int k8 = 0; k8 < 8; ++k8){
            short8 tv = *(const short8*)&ts[k8 * 8];
            #pragma unroll
            for (int u = 0; u < 8; ++u) acc += bf2f((unsigned short)tv[u]) * g[k8 * 8 + u];
        }
        atomicAdd(&agg[((size_t)dsts[j] << 6) + o], acc);
    }
}

// ---------------- combine (MFMA root GEMM); L2: LDS-staged conflict-free pooling ----------
template<int L2>
__global__ void __launch_bounds__(256) combine_kernel(
        const float* __restrict__ agg, const float* __restrict__ hx,
        const unsigned short* __restrict__ rootT, const float* __restrict__ bias,
        float* __restrict__ outp, const int* __restrict__ batch, float* __restrict__ hg){
    __shared__ float otile[64][65];
    int b = blockIdx.x, tid = threadIdx.x;
    int wid = tid >> 6, l = tid & 63;
    int m16 = l & 15, grp = l >> 4;
    int node = b * 64 + wid * 16 + m16;
    int lnode = wid * 16 + m16;
    bool ok = node < N_NODES;
    short8 h0 = {0,0,0,0,0,0,0,0}, h1 = {0,0,0,0,0,0,0,0};
    if (ok){
        const float* hp = hx + ((size_t)node << 6) + grp * 8;
        h0 = pack_bf8(*(const float4*)hp, *(const float4*)(hp + 4));
        h1 = pack_bf8(*(const float4*)(hp + 32), *(const float4*)(hp + 36));
    }
    #pragma unroll
    for (int TB = 0; TB < 64; TB += 16){
        short8 c0 = *(const short8*)(rootT + (TB + m16) * 64 + grp * 8);
        short8 c1 = *(const short8*)(rootT + (TB + m16) * 64 + 32 + grp * 8);
        f32x4 acc;
        if (ok){
            f32x4 av = *(const f32x4*)(agg + ((size_t)node << 6) + TB + grp * 4);
            f32x4 bv = *(const f32x4*)(bias + TB + grp * 4);
            acc[0] = av[0] + bv[0]; acc[1] = av[1] + bv[1];
            acc[2] = av[2] + bv[2]; acc[3] = av[3] + bv[3];
        } else {
            acc[0] = acc[1] = acc[2] = acc[3] = 0.f;
        }
        acc = __builtin_amdgcn_mfma_f32_16x16x32_bf16(c0, h0, acc, 0, 0, 0);
        acc = __builtin_amdgcn_mfma_f32_16x16x32_bf16(c1, h1, acc, 0, 0, 0);
        if (L2){
            #pragma unroll
            for (int r = 0; r < 4; ++r) otile[lnode][TB + grp * 4 + r] = lrelu(acc[r]);
        } else if (ok){
            f32x4 rv;
            rv[0] = lrelu(acc[0]); rv[1] = lrelu(acc[1]);
            rv[2] = lrelu(acc[2]); rv[3] = lrelu(acc[3]);
            *(f32x4*)(outp + ((size_t)node << 6) + TB + grp * 4) = rv;
        }
    }
    if (L2){
        __syncthreads();
        #pragma unroll
        for (int p = 0; p < 16; ++p){
            int ln = wid * 16 + p;
            int n = b * 64 + ln;
            if (n < N_NODES)
                atomicAdd(&hg[batch[n] * 64 + l], otile[ln][l]);
        }
    }
}

__global__ void head_kernel(const float* __restrict__ hg, const float* __restrict__ fc1w,
                            const float* __restrict__ fc1b, const float* __restrict__ fc2w,
                            const float* __restrict__ fc2b, float* __restrict__ out){
    int g = threadIdx.x;
    const float* row = hg + g * 64;
    float h1[32];
    #pragma unroll
    for (int j = 0; j < 32; ++j){
        float a = fc1b[j];
        #pragma unroll 8
        for (int i = 0; i < 64; ++i) a += row[i] * fc1w[i * 32 + j];
        h1[j] = lrelu(a);
    }
    float o = fc2b[0];
    #pragma unroll
    for (int j = 0; j < 32; ++j) o += h1[j] * fc2w[j];
    out[g] = o;
}

extern "C" void kernel_launch(void* const* d_in, const int* in_sizes, int n_in,
                              void* d_out, int out_size, void* d_ws, size_t ws_size,
                              hipStream_t stream){
    const float* x      = (const float*)d_in[0];
    const int*   ei     = (const int*)  d_in[1];
    const float* ea     = (const float*)d_in[2];
    const int*   batch  = (const int*)  d_in[3];
    const float* nfc_w  = (const float*)d_in[4];
    const float* nfc_b  = (const float*)d_in[5];
    const float* e1w1   = (const float*)d_in[6];
    const float* e1b1   = (const float*)d_in[7];
    const float* e1w2   = (const float*)d_in[8];
    const float* e1b2   = (const float*)d_in[9];
    const float* g1root = (const float*)d_in[10];
    const float* g1bias = (const float*)d_in[11];
    const float* e2w1   = (const float*)d_in[12];
    const float* e2b1   = (const float*)d_in[13];
    const float* e2w2   = (const float*)d_in[14];
    const float* e2b2   = (const float*)d_in[15];
    const float* g2root = (const float*)d_in[16];
    const float* g2bias = (const float*)d_in[17];
    const float* fc1w   = (const float*)d_in[18];
    const float* fc1b   = (const float*)d_in[19];
    const float* fc2w   = (const float*)d_in[20];
    const float* fc2b   = (const float*)d_in[21];
    float* out = (float*)d_out;

    const int* src = ei;
    const int* dst = ei + N_EDGES;

    // workspace carve-up
    char* ws = (char*)d_ws;
    float* hx1 = (float*)ws;               ws += (size_t)N_NODES * 64 * 4;
    float* hx2 = (float*)ws;               ws += (size_t)N_NODES * 64 * 4;
    unsigned short* tp1 = (unsigned short*)ws; ws += (size_t)N_EDGES * 64 * 2;
    unsigned short* tp2 = (unsigned short*)ws; ws += (size_t)N_EDGES * 64 * 2;
    float* hb2 = (float*)ws;               ws += (size_t)N_NODES * 64 * 4;
    float* agg = (float*)ws;               ws += (size_t)N_NODES * 64 * 4;
    float* hg  = (float*)ws;               ws += (size_t)N_GRAPHS * 64 * 4;
    unsigned short* w2t1 = (unsigned short*)ws; ws += (size_t)64 * 64 * 64 * 2;
    unsigned short* w2t2 = (unsigned short*)ws; ws += (size_t)64 * 64 * 64 * 2;
    unsigned short* nfc_wt = (unsigned short*)ws; ws += (size_t)8192 * 2;
    unsigned short* w1t1 = (unsigned short*)ws; ws += (size_t)2048 * 2;
    unsigned short* w1t2 = (unsigned short*)ws; ws += (size_t)2048 * 2;
    unsigned short* b2t1 = (unsigned short*)ws; ws += (size_t)4096 * 2;
    unsigned short* b2t2 = (unsigned short*)ws; ws += (size_t)4096 * 2;
    unsigned short* rootT1 = (unsigned short*)ws; ws += (size_t)4096 * 2;
    unsigned short* rootT2 = (unsigned short*)ws; ws += (size_t)4096 * 2;
    int* counts = (int*)ws;                ws += (size_t)10240 * 4;
    int* cursor = (int*)ws;                ws += (size_t)10240 * 4;
    int* rowptr = (int*)ws;                ws += (size_t)10240 * 4;
    int* eidx   = (int*)ws;                ws += (size_t)N_EDGES * 4;
    int* dsts   = (int*)ws;                ws += (size_t)N_EDGES * 4;
    unsigned char* G = (unsigned char*)ws;  // 41 MB fp8

    // 1: init; 2: pre (nodeFC | t-GEMMs | w2conv | count); 3: scan
    init_kernel<<<47, 256, 0, stream>>>(counts, nfc_w, nfc_wt,
        e1w1, w1t1, e2w1, w1t2, e1b2, b2t1, e2b2, b2t2, g1root, rootT1, g2root, rootT2);
    pre_kernel<<<PRE_NFC + PRE_TG + PRE_W2C + PRE_CNT, 256, 0, stream>>>(
        x, nfc_wt, nfc_b, hx1, ea, w1t1, e1b1, tp1, w1t2, e2b1, tp2,
        e1w2, w2t1, e2w2, w2t2, src, counts);
    csr_scan_kernel<<<1, 256, 0, stream>>>(counts, rowptr, cursor);

    // ---------- layer 1 (4,5,6) — scatter folded into layerA as extra parallel blocks ------
    layerA_kernel<0, 1><<<NBH2 + NBG + 250, 256, 0, stream>>>(
        hx1, b2t1, hb2, agg, w2t1, G, nullptr, src, dst, rowptr, cursor, eidx, dsts);
    msg_csr_kernel<<<N_NODES, 64, 0, stream>>>(tp1, G, hb2, rowptr, eidx, dsts, agg);
    combine_kernel<0><<<157, 256, 0, stream>>>(agg, hx1, rootT1, g1bias, hx2, batch, nullptr);

    // ---------- layer 2 (7,8,9) ----------
    layerA_kernel<1, 0><<<NBH2 + NBG + 1, 256, 0, stream>>>(
        hx2, b2t2, hb2, agg, w2t2, G, hg, src, dst, rowptr, cursor, eidx, dsts);
    msg_csr_kernel<<<N_NODES, 64, 0, stream>>>(tp2, G, hb2, rowptr, eidx, dsts, agg);
    combine_kernel<1><<<157, 256, 0, stream>>>(agg, hx2, rootT2, g2bias, nullptr, batch, hg);

    // 10: head
    head_kernel<<<1, 64, 0, stream>>>(hg, fc1w, fc1b, fc2w, fc2b, out);
}